// Round 4
// baseline (176.118 us; speedup 1.0000x reference)
//
#include <hip/hip_runtime.h>

#define N_NODES 50000
#define NEDGE 800000
#define NEDGE4 (NEDGE / 4)   // 200000 int4s
#define CONVB 1563           // ceil(800000 float4 / 512)
#define PARTB 391            // ceil(200000 int4 / 512)
#define NBUCKET 782          // one 64-node tile per fused block
#define NCAP 64              // per-node slab capacity (mean deg 16, P(>=64)~3e-22)
#define NDEG 50176           // gdeg allocation (50000 rounded up)

typedef __attribute__((ext_vector_type(8))) short bf16x8;
typedef __attribute__((ext_vector_type(4))) float f32x4;
typedef __attribute__((ext_vector_type(2))) float f32x2;

// ws layout:
//   fb8   [N_NODES*16]    uint: fp8-e4m3 features            3.2 MB
//   fbh   [N_NODES*64]    ushort: bf16 features              6.4 MB
//   wbs   [16384]         ushort: W in MFMA B-frag layout    32 KB
//   gdeg  [NDEG]          int: per-node degree (atomic)      200 KB
//   esort [N_NODES*NCAP]  uint: cols grouped by dest node    12.8 MB

__device__ __forceinline__ unsigned short f2bf(float x) {
    unsigned int u = __float_as_uint(x);
    unsigned int r = (u + 0x7FFFu + ((u >> 16) & 1u)) >> 16;  // RNE
    return (unsigned short)r;
}

// decode 16 fp8 (uint4) and accumulate into a[0..15]
__device__ __forceinline__ void acc16_fp8(float* a, uint4 v) {
    f32x2 t;
    t = __builtin_amdgcn_cvt_pk_f32_fp8(v.x, false); a[0] += t[0];  a[1] += t[1];
    t = __builtin_amdgcn_cvt_pk_f32_fp8(v.x, true);  a[2] += t[0];  a[3] += t[1];
    t = __builtin_amdgcn_cvt_pk_f32_fp8(v.y, false); a[4] += t[0];  a[5] += t[1];
    t = __builtin_amdgcn_cvt_pk_f32_fp8(v.y, true);  a[6] += t[0];  a[7] += t[1];
    t = __builtin_amdgcn_cvt_pk_f32_fp8(v.z, false); a[8] += t[0];  a[9] += t[1];
    t = __builtin_amdgcn_cvt_pk_f32_fp8(v.z, true);  a[10] += t[0]; a[11] += t[1];
    t = __builtin_amdgcn_cvt_pk_f32_fp8(v.w, false); a[12] += t[0]; a[13] += t[1];
    t = __builtin_amdgcn_cvt_pk_f32_fp8(v.w, true);  a[14] += t[0]; a[15] += t[1];
}

// K1: three jobs by block range, part FIRST so the latency-bound scatter
// overlaps the BW-bound convert:
//   [0, PARTB)             edge scatter via device-scope atomics
//   [PARTB, PARTB+CONVB)   feat -> fp8 + bf16 convert
//   [PARTB+CONVB]          W -> MFMA B-fragment bf16 pack
// gdeg is zeroed by hipMemsetAsync before this dispatch.
__global__ __launch_bounds__(512) void build_kernel(
    const float* __restrict__ feat, unsigned int* __restrict__ fb8,
    unsigned short* __restrict__ fbh,
    const int* __restrict__ row, const int* __restrict__ col,
    const float* __restrict__ W, unsigned short* __restrict__ wbs,
    int* __restrict__ gdeg, unsigned int* __restrict__ esort) {
    const int b = blockIdx.x;
    const int t = threadIdx.x;

    if (b < PARTB) {
        int i4 = b * 512 + t;
        if (i4 < NEDGE4) {
            int4 rv = ((const int4*)row)[i4];
            int4 cv = ((const int4*)col)[i4];
            int rr[4] = {rv.x, rv.y, rv.z, rv.w};
            int cc[4] = {cv.x, cv.y, cv.z, cv.w};
#pragma unroll
            for (int j = 0; j < 4; j++) {
                int pos = atomicAdd(&gdeg[rr[j]], 1);
                if (pos < NCAP)  // swap at device-coherent point: lines merge once
                    atomicExch(&esort[(size_t)rr[j] * NCAP + pos],
                               (unsigned int)cc[j]);
            }
        }
    } else if (b < PARTB + CONVB) {
        int i = (b - PARTB) * 512 + t;
        if (i < N_NODES * 16) {
            float4 v = ((const float4*)feat)[i];
            unsigned int p = 0;
            p = __builtin_amdgcn_cvt_pk_fp8_f32(v.x, v.y, p, false);
            p = __builtin_amdgcn_cvt_pk_fp8_f32(v.z, v.w, p, true);
            fb8[i] = p;
            ushort4 h;
            h.x = f2bf(v.x); h.y = f2bf(v.y); h.z = f2bf(v.z); h.w = f2bf(v.w);
            ((ushort4*)fbh)[i] = h;
        }
    } else {
        // W pack: wbs[((nt*4+kblk)*64+lane)*8+j] =
        //   bf16(W[(kblk*32+(lane>>4)*8+j)*128 + nt*16+(lane&15)])
        for (int i = t; i < 16384; i += 512) {
            int j = i & 7;
            int lane = (i >> 3) & 63;
            int kblk = (i >> 9) & 3;
            int nt = i >> 11;
            int k = kblk * 32 + (lane >> 4) * 8 + j;
            int n = nt * 16 + (lane & 15);
            wbs[i] = f2bf(W[k * 128 + n]);
        }
    }
}

// K2: direct slab gather into registers + staging + MFMA GEMM + ReLU.
// 64 nodes / 256 threads; 4 lanes per node, 16 features per lane.
__global__ __launch_bounds__(256) void fused_kernel(
    const unsigned int* __restrict__ fb8,
    const unsigned short* __restrict__ fbh,
    const int* __restrict__ gdeg,
    const unsigned int* __restrict__ esort,
    const unsigned short* __restrict__ wbs,
    float* __restrict__ out) {
    __shared__ unsigned short cbuf[64][136];  // 17.4 KB; rows 16B-aligned

    const int t = threadIdx.x;
    const int blk = blockIdx.x;
    const int base = blk * 64;
    const int g = t & 3;   // 16-byte fp8 chunk (16 feats)
    const int s = t >> 2;  // node slot 0..63
    const int node = base + s;

    const int dtrue = (node < N_NODES) ? gdeg[node] : 0;
    const int d = (dtrue < NCAP) ? dtrue : NCAP;
    const unsigned int* ep = esort + (size_t)node * NCAP;

    float a[16];
#pragma unroll
    for (int j = 0; j < 16; j++) a[j] = 0.f;

    int p = 0;
    for (; p + 4 <= d; p += 4) {
        uint4 c4 = *(const uint4*)(ep + p);  // 4 cols, 16B-aligned slab
        uint4 v0 = ((const uint4*)(fb8 + (size_t)c4.x * 16))[g];
        uint4 v1 = ((const uint4*)(fb8 + (size_t)c4.y * 16))[g];
        uint4 v2 = ((const uint4*)(fb8 + (size_t)c4.z * 16))[g];
        uint4 v3 = ((const uint4*)(fb8 + (size_t)c4.w * 16))[g];
        acc16_fp8(a, v0); acc16_fp8(a, v1);
        acc16_fp8(a, v2); acc16_fp8(a, v3);
    }
    for (; p < d; p++) {
        unsigned int c0 = ep[p];
        uint4 v0 = ((const uint4*)(fb8 + (size_t)c0 * 16))[g];
        acc16_fp8(a, v0);
    }

    // Stage combined tile (bf16): own feats [0,64) + normalized neigh [64,128)
    {
        float rd = 1.0f / (float)(dtrue + 1);
#pragma unroll
        for (int q = 0; q < 4; q++) {
            ushort4 o;
            o.x = f2bf(a[q * 4 + 0] * rd);
            o.y = f2bf(a[q * 4 + 1] * rd);
            o.z = f2bf(a[q * 4 + 2] * rd);
            o.w = f2bf(a[q * 4 + 3] * rd);
            *(ushort4*)&cbuf[s][64 + g * 16 + q * 4] = o;
        }
        if (node < N_NODES) {
            const uint4* hp = (const uint4*)(fbh + (size_t)node * 64 + g * 16);
            *(uint4*)&cbuf[s][g * 16] = hp[0];
            *(uint4*)&cbuf[s][g * 16 + 8] = hp[1];
        } else {
            uint4 z = make_uint4(0, 0, 0, 0);
            *(uint4*)&cbuf[s][g * 16] = z;
            *(uint4*)&cbuf[s][g * 16 + 8] = z;
        }
    }
    __syncthreads();

    // MFMA GEMM: wave w handles rows w*16..w*16+15, all 128 cols.
    {
        const int lane = t & 63;
        const int wave = t >> 6;
        const int quad = lane >> 4;
        const int l15 = lane & 15;

        f32x4 acc[8];
#pragma unroll
        for (int nt = 0; nt < 8; nt++) acc[nt] = (f32x4){0.f, 0.f, 0.f, 0.f};

#pragma unroll
        for (int kblk = 0; kblk < 4; kblk++) {
            bf16x8 af = *(const bf16x8*)&cbuf[wave * 16 + l15][kblk * 32 + quad * 8];
            const unsigned short* wp = wbs + kblk * 512 + lane * 8;
#pragma unroll
            for (int nt = 0; nt < 8; nt++) {
                bf16x8 bf = *(const bf16x8*)(wp + nt * 2048);
                acc[nt] = __builtin_amdgcn_mfma_f32_16x16x32_bf16(af, bf, acc[nt], 0, 0, 0);
            }
        }

        // D layout: col = lane&15, row = quad*4 + reg
#pragma unroll
        for (int nt = 0; nt < 8; nt++) {
#pragma unroll
            for (int r = 0; r < 4; r++) {
                int gr = base + wave * 16 + quad * 4 + r;
                if (gr < N_NODES)
                    out[(size_t)gr * 128 + nt * 16 + l15] = fmaxf(acc[nt][r], 0.f);
            }
        }
    }
}

extern "C" void kernel_launch(void* const* d_in, const int* in_sizes, int n_in,
                              void* d_out, int out_size, void* d_ws, size_t ws_size,
                              hipStream_t stream) {
    const float* feat = (const float*)d_in[0];
    const int* row = (const int*)d_in[1];
    const int* col = (const int*)d_in[2];
    const float* W = (const float*)d_in[3];
    float* out = (float*)d_out;

    unsigned int* fb8 = (unsigned int*)d_ws;                              // 3.2 MB
    unsigned short* fbh = (unsigned short*)(fb8 + (size_t)N_NODES * 16);  // 6.4 MB
    unsigned short* wbs = fbh + (size_t)N_NODES * 64;                     // 32 KB
    int* gdeg = (int*)(wbs + 16384);                                      // 200 KB
    unsigned int* esort = (unsigned int*)(gdeg + NDEG);                   // 12.8 MB

    hipMemsetAsync(gdeg, 0, (size_t)NDEG * sizeof(int), stream);
    build_kernel<<<PARTB + CONVB + 1, 512, 0, stream>>>(feat, fb8, fbh, row, col,
                                                        W, wbs, gdeg, esort);
    fused_kernel<<<NBUCKET, 256, 0, stream>>>(fb8, fbh, gdeg, esort, wbs, out);
}

// Round 5
// 111.870 us; speedup vs baseline: 1.5743x; 1.5743x over previous
//
#include <hip/hip_runtime.h>

#define N_NODES 50000
#define NEDGE 800000
#define NEDGE4 (NEDGE / 4)   // 200000 int4s
#define CONVB 1563           // ceil(800000 float4 / 512)
#define PARTB 196            // partition blocks, 4096 edges each
#define NBUCKET 782          // one bucket per 64-node fused tile
#define SCAP 32              // per-(bucket,part-block) cap (mean 5.2, ~1e-15 tail)
#define NCAP 64              // per-node slab capacity (deg mean 16, P(>=64)~1e-19)
#define SSTR 68              // slab row stride in uints (bank-quad rotation, 16B-aligned)

typedef __attribute__((ext_vector_type(8))) short bf16x8;
typedef __attribute__((ext_vector_type(4))) float f32x4;
typedef __attribute__((ext_vector_type(2))) float f32x2;

// ws layout:
//   fb8   [N_NODES*16]           uint: fp8-e4m3 features        3.2 MB
//   fbh   [N_NODES*64]           ushort: bf16 features          6.4 MB
//   wbs   [16384]                ushort: W in MFMA B-frag layout 32 KB
//   cnts  [NBUCKET*PARTB]        int: per-(bucket,part) counts  613 KB
//   tbuf  [NBUCKET*PARTB*SCAP]   uint packed (localrow<<17)|col 19.6 MB

__device__ __forceinline__ unsigned short f2bf(float x) {
    unsigned int u = __float_as_uint(x);
    unsigned int r = (u + 0x7FFFu + ((u >> 16) & 1u)) >> 16;  // RNE
    return (unsigned short)r;
}

// decode 16 fp8 (uint4) and accumulate into a[0..15]
__device__ __forceinline__ void acc16_fp8(float* a, uint4 v) {
    f32x2 t;
    t = __builtin_amdgcn_cvt_pk_f32_fp8(v.x, false); a[0] += t[0];  a[1] += t[1];
    t = __builtin_amdgcn_cvt_pk_f32_fp8(v.x, true);  a[2] += t[0];  a[3] += t[1];
    t = __builtin_amdgcn_cvt_pk_f32_fp8(v.y, false); a[4] += t[0];  a[5] += t[1];
    t = __builtin_amdgcn_cvt_pk_f32_fp8(v.y, true);  a[6] += t[0];  a[7] += t[1];
    t = __builtin_amdgcn_cvt_pk_f32_fp8(v.z, false); a[8] += t[0];  a[9] += t[1];
    t = __builtin_amdgcn_cvt_pk_f32_fp8(v.z, true);  a[10] += t[0]; a[11] += t[1];
    t = __builtin_amdgcn_cvt_pk_f32_fp8(v.w, false); a[12] += t[0]; a[13] += t[1];
    t = __builtin_amdgcn_cvt_pk_f32_fp8(v.w, true);  a[14] += t[0]; a[15] += t[1];
}

// K1: three independent jobs by block range (latency-bound partition FIRST so it
// overlaps the BW-bound convert):
//   [0, PARTB)             edge partition into private per-(bucket,block) segments
//   [PARTB, PARTB+CONVB)   feat -> fp8 + bf16 convert
//   [PARTB+CONVB]          W -> MFMA B-fragment bf16 pack
__global__ __launch_bounds__(512) void build_kernel(
    const float* __restrict__ feat, unsigned int* __restrict__ fb8,
    unsigned short* __restrict__ fbh,
    const int* __restrict__ row, const int* __restrict__ col,
    const float* __restrict__ W, unsigned short* __restrict__ wbs,
    int* __restrict__ cnts, unsigned int* __restrict__ tbuf) {
    __shared__ int lcur[NBUCKET];
    const int b = blockIdx.x;
    const int t = threadIdx.x;

    if (b < PARTB) {
        const int hb = b;
        for (int i = t; i < NBUCKET; i += 512) lcur[i] = 0;
        __syncthreads();

        const int base4 = hb * 1024;  // 4096 edges per block
        int4 rv[2], cv[2];
#pragma unroll
        for (int k = 0; k < 2; k++) {
            int i4 = base4 + k * 512 + t;
            if (i4 < NEDGE4) {
                rv[k] = ((const int4*)row)[i4];
                cv[k] = ((const int4*)col)[i4];
            } else {
                rv[k] = make_int4(-1, -1, -1, -1);
                cv[k] = make_int4(0, 0, 0, 0);
            }
        }

#pragma unroll
        for (int k = 0; k < 2; k++) {
            if (rv[k].x < 0) continue;
            int rr[4] = {rv[k].x, rv[k].y, rv[k].z, rv[k].w};
            int cc[4] = {cv[k].x, cv[k].y, cv[k].z, cv[k].w};
#pragma unroll
            for (int j = 0; j < 4; j++) {
                int bk = rr[j] >> 6;
                int pos = atomicAdd(&lcur[bk], 1);
                if (pos < SCAP)
                    tbuf[((size_t)bk * PARTB + hb) * SCAP + pos] =
                        ((unsigned int)(rr[j] & 63) << 17) | (unsigned int)cc[j];
            }
        }
        __syncthreads();
        // transposed: cnts[bucket][part] so fused reads are coalesced
        for (int i = t; i < NBUCKET; i += 512) {
            int c = lcur[i];
            cnts[i * PARTB + hb] = (c < SCAP) ? c : SCAP;
        }
    } else if (b < PARTB + CONVB) {
        int i = (b - PARTB) * 512 + t;
        if (i < N_NODES * 16) {
            float4 v = ((const float4*)feat)[i];
            unsigned int p = 0;
            p = __builtin_amdgcn_cvt_pk_fp8_f32(v.x, v.y, p, false);
            p = __builtin_amdgcn_cvt_pk_fp8_f32(v.z, v.w, p, true);
            fb8[i] = p;
            ushort4 h;
            h.x = f2bf(v.x); h.y = f2bf(v.y); h.z = f2bf(v.z); h.w = f2bf(v.w);
            ((ushort4*)fbh)[i] = h;
        }
    } else {
        // W pack: wbs[((nt*4+kblk)*64+lane)*8+j] =
        //   bf16(W[(kblk*32+(lane>>4)*8+j)*128 + nt*16+(lane&15)])
        for (int i = t; i < 16384; i += 512) {
            int j = i & 7;
            int lane = (i >> 3) & 63;
            int kblk = (i >> 9) & 3;
            int nt = i >> 11;
            int k = kblk * 32 + (lane >> 4) * 8 + j;
            int n = nt * 16 + (lane & 15);
            wbs[i] = f2bf(W[k * 128 + n]);
        }
    }
}

// K2: cheap merge (thread h owns segment h: 1 LDS atomic + 1 ds_write per edge),
// then register gather from LDS slab + staging + MFMA GEMM + ReLU.
// 64 nodes / 256 threads; 4 lanes per node, 16 features per lane.
__global__ __launch_bounds__(256) void fused_kernel(
    const unsigned int* __restrict__ fb8,
    const unsigned short* __restrict__ fbh,
    const int* __restrict__ cnts,
    const unsigned int* __restrict__ tbuf,
    const unsigned short* __restrict__ wbs,
    float* __restrict__ out) {
    __shared__ unsigned int slab[64 * SSTR];  // 17.4 KB, cols grouped per node
    __shared__ int scnt[64];
    __shared__ unsigned short cbuf[64][136];  // 17.4 KB; rows 16B-aligned

    const int t = threadIdx.x;
    const int blk = blockIdx.x;
    const int base = blk * 64;
    const size_t seg0 = (size_t)blk * PARTB * SCAP;

    if (t < 64) scnt[t] = 0;
    __syncthreads();

    // Phase 1: direct segment ownership — no scan, no search, no rank pass.
    if (t < PARTB) {
        int c = cnts[blk * PARTB + t];
        const unsigned int* sp = tbuf + seg0 + t * SCAP;
        for (int j = 0; j < c; j++) {
            unsigned int p = sp[j];
            int lr = (int)(p >> 17);
            int pos = atomicAdd(&scnt[lr], 1);
            if (pos < NCAP) slab[lr * SSTR + pos] = p & 0x1FFFFu;
        }
    }
    __syncthreads();

    const int g = t & 3;   // 16-byte fp8 chunk (16 feats)
    const int s = t >> 2;  // node slot 0..63
    const int node = base + s;

    const int dtrue = scnt[s];
    const int d = (dtrue < NCAP) ? dtrue : NCAP;
    const unsigned int* sl = &slab[s * SSTR];

    float a[16];
#pragma unroll
    for (int j = 0; j < 16; j++) a[j] = 0.f;

    int p = 0;
    for (; p + 4 <= d; p += 4) {
        uint4 c4 = *(const uint4*)(sl + p);  // ds_read_b128, 4-lane broadcast
        uint4 v0 = ((const uint4*)(fb8 + (size_t)c4.x * 16))[g];
        uint4 v1 = ((const uint4*)(fb8 + (size_t)c4.y * 16))[g];
        uint4 v2 = ((const uint4*)(fb8 + (size_t)c4.z * 16))[g];
        uint4 v3 = ((const uint4*)(fb8 + (size_t)c4.w * 16))[g];
        acc16_fp8(a, v0); acc16_fp8(a, v1);
        acc16_fp8(a, v2); acc16_fp8(a, v3);
    }
    for (; p < d; p++) {
        unsigned int c0 = sl[p];
        uint4 v0 = ((const uint4*)(fb8 + (size_t)c0 * 16))[g];
        acc16_fp8(a, v0);
    }

    // Stage combined tile (bf16): own feats [0,64) + normalized neigh [64,128)
    {
        float rd = 1.0f / (float)(dtrue + 1);
#pragma unroll
        for (int q = 0; q < 4; q++) {
            ushort4 o;
            o.x = f2bf(a[q * 4 + 0] * rd);
            o.y = f2bf(a[q * 4 + 1] * rd);
            o.z = f2bf(a[q * 4 + 2] * rd);
            o.w = f2bf(a[q * 4 + 3] * rd);
            *(ushort4*)&cbuf[s][64 + g * 16 + q * 4] = o;
        }
        if (node < N_NODES) {
            const uint4* hp = (const uint4*)(fbh + (size_t)node * 64 + g * 16);
            *(uint4*)&cbuf[s][g * 16] = hp[0];
            *(uint4*)&cbuf[s][g * 16 + 8] = hp[1];
        } else {
            uint4 z = make_uint4(0, 0, 0, 0);
            *(uint4*)&cbuf[s][g * 16] = z;
            *(uint4*)&cbuf[s][g * 16 + 8] = z;
        }
    }
    __syncthreads();

    // MFMA GEMM: wave w handles rows w*16..w*16+15, all 128 cols.
    {
        const int lane = t & 63;
        const int wave = t >> 6;
        const int quad = lane >> 4;
        const int l15 = lane & 15;

        f32x4 acc[8];
#pragma unroll
        for (int nt = 0; nt < 8; nt++) acc[nt] = (f32x4){0.f, 0.f, 0.f, 0.f};

#pragma unroll
        for (int kblk = 0; kblk < 4; kblk++) {
            bf16x8 af = *(const bf16x8*)&cbuf[wave * 16 + l15][kblk * 32 + quad * 8];
            const unsigned short* wp = wbs + kblk * 512 + lane * 8;
#pragma unroll
            for (int nt = 0; nt < 8; nt++) {
                bf16x8 bf = *(const bf16x8*)(wp + nt * 2048);
                acc[nt] = __builtin_amdgcn_mfma_f32_16x16x32_bf16(af, bf, acc[nt], 0, 0, 0);
            }
        }

        // D layout: col = lane&15, row = quad*4 + reg
#pragma unroll
        for (int nt = 0; nt < 8; nt++) {
#pragma unroll
            for (int r = 0; r < 4; r++) {
                int gr = base + wave * 16 + quad * 4 + r;
                if (gr < N_NODES)
                    out[(size_t)gr * 128 + nt * 16 + l15] = fmaxf(acc[nt][r], 0.f);
            }
        }
    }
}

extern "C" void kernel_launch(void* const* d_in, const int* in_sizes, int n_in,
                              void* d_out, int out_size, void* d_ws, size_t ws_size,
                              hipStream_t stream) {
    const float* feat = (const float*)d_in[0];
    const int* row = (const int*)d_in[1];
    const int* col = (const int*)d_in[2];
    const float* W = (const float*)d_in[3];
    float* out = (float*)d_out;

    unsigned int* fb8 = (unsigned int*)d_ws;                              // 3.2 MB
    unsigned short* fbh = (unsigned short*)(fb8 + (size_t)N_NODES * 16);  // 6.4 MB
    unsigned short* wbs = fbh + (size_t)N_NODES * 64;                     // 32 KB
    int* cnts = (int*)(wbs + 16384);                                      // 613 KB
    unsigned int* tbuf = (unsigned int*)(cnts + (size_t)NBUCKET * PARTB); // 19.6 MB

    build_kernel<<<PARTB + CONVB + 1, 512, 0, stream>>>(feat, fb8, fbh, row, col,
                                                        W, wbs, cnts, tbuf);
    fused_kernel<<<NBUCKET, 256, 0, stream>>>(fb8, fbh, cnts, tbuf, wbs, out);
}